// Round 8
// baseline (78.256 us; speedup 1.0000x reference)
//
#include <hip/hip_runtime.h>
#include <hip/hip_fp16.h>
#include <math.h>

#define NQ 8
#define DK 64
#define NB 8
#define NS 1024
#define RB 4            // rows per block in attn kernel (1 row per wave)

typedef _Float16 h2v __attribute__((ext_vector_type(2)));

__device__ __forceinline__ float fdot2h(unsigned qu, unsigned ku, float acc) {
#if defined(__has_builtin) && __has_builtin(__builtin_amdgcn_fdot2)
    union { unsigned u; h2v h; } a, b;
    a.u = qu; b.u = ku;
    return __builtin_amdgcn_fdot2(a.h, b.h, acc, false);
#else
    __half2 qh = *(__half2*)&qu, kh = *(__half2*)&ku;
    float2 qf = __half22float2(qh), kf = __half22float2(kh);
    return fmaf(qf.x, kf.x, fmaf(qf.y, kf.y, acc));
#endif
}

// ---------------- prep: values GEMM (blocks 0..2047) + density features (2048..2303) ----------------
// qdh/kdh fp16 [tok][n*4 + {d0,d1,re,im}]; factor 2 folded into kdh cross terms.
__global__ __launch_bounds__(256) void prep_kernel(
    const float* __restrict__ x,
    const float* __restrict__ theta_q,
    const float* __restrict__ theta_k,
    const float* __restrict__ Wv,
    const float* __restrict__ bv,
    __half* __restrict__ qdh, __half* __restrict__ kdh,
    float* __restrict__ values) {
    int bid = blockIdx.x;
    int tid = threadIdx.x;
    if (bid < 2048) {
        // values = x @ Wv^T + bv (4 partial chains)
        int t = bid * 4 + (tid >> 6);
        int d = tid & 63;
        const float4* xr = (const float4*)(x + (size_t)t * DK);
        const float4* wr = (const float4*)(Wv + (size_t)d * DK);
        float a0 = bv[d], a1 = 0.f, a2 = 0.f, a3 = 0.f;
#pragma unroll
        for (int j = 0; j < DK / 4; ++j) {
            float4 xv = xr[j], wv = wr[j];
            a0 = fmaf(xv.x, wv.x, a0);
            a1 = fmaf(xv.y, wv.y, a1);
            a2 = fmaf(xv.z, wv.z, a2);
            a3 = fmaf(xv.w, wv.w, a3);
        }
        values[(size_t)t * DK + d] = (a0 + a1) + (a2 + a3);
    } else {
        int gid = (bid - 2048) * 256 + tid;   // 0..65535
        int tok = gid >> 3;
        int n = gid & 7;
        float xin = x[(size_t)tok * DK + n];
        float ex = __expf(2.0f * xin);               // fast tanh
        float xn = 1.0f - 2.0f / (ex + 1.0f);
        float half = xn * 1.57079632679489662f;      // xn * pi/2
        float s, c;
        __sincosf(half, &s, &c);

        // Q side
        {
            float phi = theta_q[n * 3 + 0], th = theta_q[n * 3 + 1], om = theta_q[n * 3 + 2];
            float st, ct; __sincosf(0.5f * th, &st, &ct);
            float smpo, cmpo; __sincosf(0.5f * (phi + om), &smpo, &cmpo);
            float spmo, cpmo; __sincosf(0.5f * (phi - om), &spmo, &cpmo);
            float a = ct * c, b = st * s, cc = st * c, d = ct * s;
            float a0re =  cmpo * a - cpmo * b;
            float a0im = -smpo * a - spmo * b;
            float a1re =  cpmo * cc + cmpo * d;
            float a1im = -spmo * cc + smpo * d;
            float d0 = fmaf(a0re, a0re, a0im * a0im);
            float d1 = fmaf(a1re, a1re, a1im * a1im);
            float ur = fmaf(a1re, a0re, a1im * a0im);
            float ui = fmaf(a1im, a0re, -a1re * a0im);
            __half2* qp = (__half2*)(qdh + (size_t)tok * 32 + n * 4);
            qp[0] = __floats2half2_rn(d0, d1);
            qp[1] = __floats2half2_rn(ur, ui);
        }
        // K side (factor 2 on cross terms)
        {
            float phi = theta_k[n * 3 + 0], th = theta_k[n * 3 + 1], om = theta_k[n * 3 + 2];
            float st, ct; __sincosf(0.5f * th, &st, &ct);
            float smpo, cmpo; __sincosf(0.5f * (phi + om), &smpo, &cmpo);
            float spmo, cpmo; __sincosf(0.5f * (phi - om), &spmo, &cpmo);
            float a = ct * c, b = st * s, cc = st * c, d = ct * s;
            float a0re =  cmpo * a - cpmo * b;
            float a0im = -smpo * a - spmo * b;
            float a1re =  cpmo * cc + cmpo * d;
            float a1im = -spmo * cc + smpo * d;
            float d0 = fmaf(a0re, a0re, a0im * a0im);
            float d1 = fmaf(a1re, a1re, a1im * a1im);
            float ur = fmaf(a1re, a0re, a1im * a0im);
            float ui = fmaf(a1im, a0re, -a1re * a0im);
            __half2* kp = (__half2*)(kdh + (size_t)tok * 32 + n * 4);
            kp[0] = __floats2half2_rn(d0, d1);
            kp[1] = __floats2half2_rn(2.f * ur, 2.f * ui);
        }
    }
}

// ---------------- attn: fused scores -> softmax -> attn + PV ----------------
// 2048 blocks x 256 threads; block = 4 rows; wave w owns row w (q in SGPRs).
__global__ __launch_bounds__(256, 6) void attn_kernel(
    const __half* __restrict__ qdh, const __half* __restrict__ kdh,
    const float* __restrict__ values,
    float* __restrict__ out, float* __restrict__ attn) {
    __shared__ float e_lds[RB][NS];   // 16 KB, reused as [16][4][64] reduce scratch
    __shared__ float inv_lds[RB];

    int tid = threadIdx.x;
    int gr0 = blockIdx.x * RB;            // global row base (= b*NS + s0)
    int b = gr0 >> 10;
    int w = tid >> 6, lane = tid & 63;

    // q density features for row w: 16 uints (32 halfs), wave-uniform -> SGPRs
    unsigned sq[16];
    {
        const unsigned* qp = (const unsigned*)(qdh + ((size_t)(gr0 + w)) * 32);
#pragma unroll
        for (int i = 0; i < 16; ++i) sq[i] = __builtin_amdgcn_readfirstlane(qp[i]);
    }

    const __half* kfb = kdh + (size_t)b * NS * 32;

    // ---- Phase 1: scores + exp; wave covers all 1024 tokens for its row ----
    float sum = 0.f;
    for (int it = 0; it < 16; ++it) {
        int t = it * 64 + lane;
        const uint4* kp = (const uint4*)(kfb + ((size_t)t) * 32);  // 64 B
        uint4 k0 = kp[0], k1 = kp[1], k2 = kp[2], k3 = kp[3];
        float m0 = fdot2h(sq[ 0], k0.x, fdot2h(sq[ 1], k0.y, 0.f));
        float m1 = fdot2h(sq[ 2], k0.z, fdot2h(sq[ 3], k0.w, 0.f));
        float m2 = fdot2h(sq[ 4], k1.x, fdot2h(sq[ 5], k1.y, 0.f));
        float m3 = fdot2h(sq[ 6], k1.z, fdot2h(sq[ 7], k1.w, 0.f));
        float m4 = fdot2h(sq[ 8], k2.x, fdot2h(sq[ 9], k2.y, 0.f));
        float m5 = fdot2h(sq[10], k2.z, fdot2h(sq[11], k2.w, 0.f));
        float m6 = fdot2h(sq[12], k3.x, fdot2h(sq[13], k3.y, 0.f));
        float m7 = fdot2h(sq[14], k3.z, fdot2h(sq[15], k3.w, 0.f));
        float core = ((m0 * m1) * (m2 * m3)) * ((m4 * m5) * (m6 * m7));
        float e = __expf(fmaf(core, 0.5f, 0.5f));   // score in [0.5,1] -> no max needed
        e_lds[w][t] = e;
        sum += e;
    }
#pragma unroll
    for (int msk = 1; msk < 64; msk <<= 1) sum += __shfl_xor(sum, msk, 64);
    if (lane == 0) inv_lds[w] = 1.f / sum;
    __syncthreads();

    // ---- Phase 2: write normalized attn (coalesced float4) ----
    float* ab = attn + (size_t)gr0 * NS;
#pragma unroll
    for (int r = 0; r < RB; ++r) {
        float4 e4 = *(const float4*)&e_lds[r][tid * 4];
        float iv = inv_lds[r];
        *(float4*)&ab[(size_t)r * NS + tid * 4] =
            make_float4(e4.x * iv, e4.y * iv, e4.z * iv, e4.w * iv);
    }

    // ---- Phase 3: PV on unnormalized e; thread (tg,dg) ----
    int tg = tid >> 4, dg = tid & 15;
    const float* vb = values + (size_t)b * NS * DK;
    float acc[RB][4];
#pragma unroll
    for (int r = 0; r < RB; ++r) { acc[r][0] = acc[r][1] = acc[r][2] = acc[r][3] = 0.f; }

    for (int jj = 0; jj < 16; ++jj) {
        int t = jj * 64 + tg * 4;
        const float* vp = vb + (size_t)t * DK + dg * 4;
        float4 v0 = *(const float4*)(vp);
        float4 v1 = *(const float4*)(vp + DK);
        float4 v2 = *(const float4*)(vp + 2 * DK);
        float4 v3 = *(const float4*)(vp + 3 * DK);
#pragma unroll
        for (int r = 0; r < RB; ++r) {
            float4 e4 = *(const float4*)&e_lds[r][t];
            acc[r][0] = fmaf(e4.x, v0.x, fmaf(e4.y, v1.x, fmaf(e4.z, v2.x, fmaf(e4.w, v3.x, acc[r][0]))));
            acc[r][1] = fmaf(e4.x, v0.y, fmaf(e4.y, v1.y, fmaf(e4.z, v2.y, fmaf(e4.w, v3.y, acc[r][1]))));
            acc[r][2] = fmaf(e4.x, v0.z, fmaf(e4.y, v1.z, fmaf(e4.z, v2.z, fmaf(e4.w, v3.z, acc[r][2]))));
            acc[r][3] = fmaf(e4.x, v0.w, fmaf(e4.y, v1.w, fmaf(e4.z, v2.w, fmaf(e4.w, v3.w, acc[r][3]))));
        }
    }

    // ---- out reduce: reuse e_lds as [16][4][64] fp32 scratch, single round ----
    __syncthreads();                       // all reads of e_lds complete
    float* red = &e_lds[0][0];
#pragma unroll
    for (int r = 0; r < RB; ++r) {
        *(float4*)&red[((size_t)tg * 4 + r) * 64 + dg * 4] =
            make_float4(acc[r][0], acc[r][1], acc[r][2], acc[r][3]);
    }
    __syncthreads();
    {
        int r2 = tid >> 6, d = tid & 63;
        float o = 0.f;
#pragma unroll
        for (int g = 0; g < 16; ++g) o += red[((size_t)g * 4 + r2) * 64 + d];
        out[((size_t)(gr0 + r2)) * DK + d] = o * inv_lds[r2];
    }
}

extern "C" void kernel_launch(void* const* d_in, const int* in_sizes, int n_in,
                              void* d_out, int out_size, void* d_ws, size_t ws_size,
                              hipStream_t stream) {
    const float* x       = (const float*)d_in[0];
    const float* theta_q = (const float*)d_in[1];
    const float* theta_k = (const float*)d_in[2];
    const float* W_v     = (const float*)d_in[3];
    const float* b_v     = (const float*)d_in[4];

    float* out  = (float*)d_out;                        // [8,1024,64]
    float* attn = (float*)d_out + (size_t)NB * NS * DK; // [8,1024,1024]

    __half* qdh    = (__half*)d_ws;                          // 512 KB fp16
    __half* kdh    = qdh + (size_t)NB * NS * 32;             // 512 KB fp16
    float*  values = (float*)(kdh + (size_t)NB * NS * 32);   // 2 MB fp32

    prep_kernel<<<2048 + NB * NS * NQ / 256, 256, 0, stream>>>(
        x, theta_q, theta_k, W_v, b_v, qdh, kdh, values);
    attn_kernel<<<NB * NS / RB, 256, 0, stream>>>(qdh, kdh, values, out, attn);
}